// Round 8
// baseline (148.565 us; speedup 1.0000x reference)
//
#include <hip/hip_runtime.h>
#include <math.h>

typedef _Float16 half8 __attribute__((ext_vector_type(8)));
typedef float floatx4 __attribute__((ext_vector_type(4)));

#define DD 256
#define HH 512
#define OC 92
#define NJ 24
#define BM 128                 // rows per block (4 waves x 32)
#define NCHUNK 16
#define W2P_OFF 131072         // halfs: padded W2 frag region (16 chunks x 4096 halfs)
#define FLAG_OFF 196608        // halfs offset of int flag block
#define FCAP 16384
#define BUF_BYTES 24576        // 16KB W1 chunk + 8KB padded W2 chunk

__constant__ int c_parent[NJ] = {-1,0,0,0,1,2,3,4,5,6,7,8,9,9,9,12,13,14,16,17,18,19,20,21};

// fragment maps (verified R2-R7):
// A/B-frag: lane l holds (non-K idx)=l&15, k = 4*(l>>4)+(j&3)+16*(j>>2)
// C/D: reg i: M-idx = 4*(l>>4)+i, N-idx = l&15
// Swapped GEMM1: mfma(W1frag, zfrag) -> lane holds batch-row=l&15, h-col=16*cf+4*(l>>4)+i
//   == GEMM2 B-frag with j = i|(cf<<2)  (register handoff, no LDS bounce)
// Swapped GEMM2: lane holds batch-row=l&15, out-col=16*cf+4*(l>>4)+i -> joint lane-local.

__global__ __launch_bounds__(256)
void prep(const float* __restrict__ W1, const float* __restrict__ W2,
          _Float16* __restrict__ ws, int* __restrict__ flags) {
    int t = blockIdx.x * 256 + threadIdx.x;     // 0..24575
    if (t == 0) flags[0] = 0;
    if (t < 16384) {
        // W1 frags: lane=t&63, cfrag=(t>>6)&1, ks=(t>>7)&7, ckI=t>>10
        int lane = t & 63;
        int cfrag = (t >> 6) & 1;
        int ks = (t >> 7) & 7;
        int ckI = t >> 10;
        int c = ckI * 32 + cfrag * 16 + (lane & 15);
        int kb = ks * 32 + 4 * (lane >> 4);
        half8 v;
        #pragma unroll
        for (int j = 0; j < 8; ++j) {
            int k = kb + (j & 3) + 16 * (j >> 2);
            v[j] = (_Float16)W1[k * HH + c];
        }
        *(half8*)(ws + t * 8) = v;
    } else {
        // padded W2 frags: 16 chunks x 8 slots x 64 lanes (slots 6,7 = zero pad)
        int u = t - 16384;                      // 0..8191
        int lane = u & 63;
        int s = (u >> 6) & 7;
        int ck = u >> 9;
        half8 v;
        if (s < 6) {
            int c = s * 16 + (lane & 15);
            int kb = ck * 32 + 4 * (lane >> 4);
            #pragma unroll
            for (int j = 0; j < 8; ++j) {
                int k = kb + (j & 3) + 16 * (j >> 2);
                v[j] = (c < OC) ? (_Float16)W2[k * OC + c] : (_Float16)0.0f;
            }
        } else {
            #pragma unroll
            for (int j = 0; j < 8; ++j) v[j] = (_Float16)0.0f;
        }
        *(half8*)(ws + W2P_OFF + ck * 4096 + (s * 64 + lane) * 8) = v;
    }
}

__global__ __launch_bounds__(256)
__attribute__((amdgpu_waves_per_eu(2, 2)))
void fused_main(const float* __restrict__ z, const _Float16* __restrict__ wsp,
                const float* __restrict__ b1, const float* __restrict__ b2,
                float* __restrict__ out, long long Btot, int* __restrict__ flags)
{
    __shared__ __align__(16) char smem[2 * BUF_BYTES + 2048 + 384];  // 51584 B
    float* b1f = (float*)(smem + 2 * BUF_BYTES);          // 512 f32
    float* b2f = (float*)(smem + 2 * BUF_BYTES + 2048);   // 96 f32
    const int tid = threadIdx.x;
    const int w   = tid >> 6;
    const int l   = tid & 63;
    const int l15 = l & 15;
    const int l4  = l >> 4;

    const long long R0  = (long long)blockIdx.x * BM;
    const long long R0w = R0 + w * 32;

// async stage of one chunk's W frags (24 x 1KB granules; wave w does 6)
#define STAGE(ck_, dstbuf_) do {                                                             \
    const char* s1g_ = (const char*)wsp + (size_t)(ck_) * 16384;                             \
    const char* s2g_ = (const char*)(wsp + W2P_OFF) + (size_t)(ck_) * 8192;                  \
    _Pragma("unroll")                                                                        \
    for (int i_ = 0; i_ < 6; ++i_) {                                                         \
        int g_ = w * 6 + i_;                                                                 \
        const char* src_ = (g_ < 16) ? (s1g_ + g_ * 1024) : (s2g_ + (g_ - 16) * 1024);       \
        __builtin_amdgcn_global_load_lds(                                                    \
            (const __attribute__((address_space(1))) void*)(src_ + l * 16),                  \
            (__attribute__((address_space(3))) void*)((dstbuf_) + g_ * 1024), 16, 0, 0);     \
    }                                                                                        \
} while (0)

// Explicit load-clustering: ALL 16 W1 ds_reads issued before the first MFMA,
// so they pipeline on the LDS pipe (lgkmcnt-counted) instead of serializing
// read->MFMA->read.  w2f loads issued before silu so silu covers their latency.
#define COMPUTE_CHUNK(bufc_, ck_) do {                                                       \
    const _Float16* s1_ = (const _Float16*)(bufc_);                                          \
    const _Float16* s2_ = (const _Float16*)((bufc_) + 16384);                                \
    half8 wf_[16];                                                                           \
    _Pragma("unroll")                                                                        \
    for (int f_ = 0; f_ < 16; ++f_) wf_[f_] = *(const half8*)(s1_ + (f_ * 64 + l) * 8);      \
    floatx4 vb1_[2];                                                                         \
    vb1_[0] = *(const floatx4*)(b1f + (ck_) * 32 + 4 * l4);                                  \
    vb1_[1] = *(const floatx4*)(b1f + (ck_) * 32 + 16 + 4 * l4);                             \
    floatx4 acc1_[2][2];                                                                     \
    acc1_[0][0] = (floatx4)0.0f; acc1_[0][1] = (floatx4)0.0f;                                \
    acc1_[1][0] = (floatx4)0.0f; acc1_[1][1] = (floatx4)0.0f;                                \
    _Pragma("unroll")                                                                        \
    for (int ks_ = 0; ks_ < 8; ++ks_) {                                                      \
        _Pragma("unroll")                                                                    \
        for (int cf_ = 0; cf_ < 2; ++cf_) {                                                  \
            acc1_[0][cf_] = __builtin_amdgcn_mfma_f32_16x16x32_f16(wf_[ks_ * 2 + cf_], zh[0][ks_], acc1_[0][cf_], 0, 0, 0); \
            acc1_[1][cf_] = __builtin_amdgcn_mfma_f32_16x16x32_f16(wf_[ks_ * 2 + cf_], zh[1][ks_], acc1_[1][cf_], 0, 0, 0); \
        }                                                                                    \
    }                                                                                        \
    half8 w2f_[6];                                                                           \
    _Pragma("unroll")                                                                        \
    for (int cf_ = 0; cf_ < 6; ++cf_) w2f_[cf_] = *(const half8*)(s2_ + (cf_ * 64 + l) * 8); \
    half8 ah_[2];                                                                            \
    _Pragma("unroll")                                                                        \
    for (int at_ = 0; at_ < 2; ++at_) {                                                      \
        _Pragma("unroll")                                                                    \
        for (int cf_ = 0; cf_ < 2; ++cf_) {                                                  \
            _Pragma("unroll")                                                                \
            for (int i_ = 0; i_ < 4; ++i_) {                                                 \
                float a_ = acc1_[at_][cf_][i_] + vb1_[cf_][i_];                              \
                float hv_ = a_ * __builtin_amdgcn_rcpf(1.0f + __expf(-a_));                  \
                ah_[at_][i_ | (cf_ << 2)] = (_Float16)hv_;                                   \
            }                                                                                \
        }                                                                                    \
    }                                                                                        \
    _Pragma("unroll")                                                                        \
    for (int cf_ = 0; cf_ < 6; ++cf_) {                                                      \
        a2[0][cf_] = __builtin_amdgcn_mfma_f32_16x16x32_f16(w2f_[cf_], ah_[0], a2[0][cf_], 0, 0, 0); \
        a2[1][cf_] = __builtin_amdgcn_mfma_f32_16x16x32_f16(w2f_[cf_], ah_[1], a2[1][cf_], 0, 0, 0); \
    }                                                                                        \
} while (0)

    // ---- prologue: stage chunk 0, biases to LDS, z fragments to regs ----
    STAGE(0, smem);
    if (tid < 128) *(floatx4*)(b1f + tid * 4) = *(const floatx4*)(b1 + tid * 4);
    if (tid >= 128 && tid < 224) { int c = tid - 128; b2f[c] = (c < OC) ? b2[c] : 0.0f; }

    half8 zh[2][8];
    #pragma unroll
    for (int at = 0; at < 2; ++at) {
        const float* zrow = z + (R0w + (long long)(at * 16 + l15)) * DD;
        #pragma unroll
        for (int ks = 0; ks < 8; ++ks) {
            const float* p = zrow + ks * 32 + l4 * 4;
            floatx4 va = *(const floatx4*)p;
            floatx4 vb = *(const floatx4*)(p + 16);
            half8 th;
            th[0] = (_Float16)va[0]; th[1] = (_Float16)va[1];
            th[2] = (_Float16)va[2]; th[3] = (_Float16)va[3];
            th[4] = (_Float16)vb[0]; th[5] = (_Float16)vb[1];
            th[6] = (_Float16)vb[2]; th[7] = (_Float16)vb[3];
            zh[at][ks] = th;
        }
    }

    floatx4 a2[2][6];
    #pragma unroll
    for (int at = 0; at < 2; ++at)
        #pragma unroll
        for (int i = 0; i < 6; ++i) a2[at][i] = (floatx4)0.0f;

    __syncthreads();   // drains stage-0 DMA + bias writes

    // ---- main loop: double-buffered, one raw barrier per chunk ----
    #pragma unroll 1
    for (int t = 0; t < 8; ++t) {
        STAGE(2 * t + 1, smem + BUF_BYTES);
        COMPUTE_CHUNK(smem, 2 * t);
        asm volatile("s_waitcnt vmcnt(0)" ::: "memory");
        __builtin_amdgcn_s_barrier();
        if (t < 7) STAGE(2 * t + 2, smem);
        COMPUTE_CHUNK(smem + BUF_BYTES, 2 * t + 1);
        asm volatile("s_waitcnt vmcnt(0)" ::: "memory");
        __builtin_amdgcn_s_barrier();
    }

    // ---- epilogue (aliases staging buffers; all waves past final barrier) ----
    float* s_off = (float*)smem + w * 3040;
    float* s_len = s_off + 2304;

    #pragma unroll
    for (int at = 0; at < 2; ++at) {
        const int r = at * 16 + l15;
        #pragma unroll
        for (int cf = 0; cf < 6; ++cf) {
            const int j = 4 * cf + l4;               // joint-1 index
            if (j < NJ - 1) {
                float x  = a2[at][cf][0] + b2f[4 * j + 0];
                float y  = a2[at][cf][1] + b2f[4 * j + 1];
                float zz = a2[at][cf][2] + b2f[4 * j + 2];
                float lr = a2[at][cf][3] + b2f[4 * j + 3];
                float nrm = sqrtf(x * x + y * y + zz * zz);
                float inv = __builtin_amdgcn_rcpf(fmaxf(nrm, 1e-6f));
                float len = fmaxf(lr, 0.0f) + __logf(1.0f + __expf(-fabsf(lr)));
                if (len > 12.0f * nrm) {             // fp16 path untrustworthy here
                    int fi = atomicAdd(&flags[0], 1);
                    if (fi < FCAP) flags[1 + fi] = (int)(R0w + r);
                }
                s_off[r * 72 + 3 * (j + 1) + 0] = x * inv * len;
                s_off[r * 72 + 3 * (j + 1) + 1] = y * inv * len;
                s_off[r * 72 + 3 * (j + 1) + 2] = zz * inv * len;
                s_len[r * 23 + j] = len;
            }
        }
    }
    if (l < 32) {
        s_off[l * 72 + 0] = 0.0f;
        s_off[l * 72 + 1] = 0.0f;
        s_off[l * 72 + 2] = 0.0f;
    }
    __syncthreads();

    float* joints  = out;
    float* offsets = out + Btot * (NJ * 3);
    float* length  = out + 2 * Btot * (NJ * 3);

    {
        float* gdst = offsets + R0w * (NJ * 3);
        #pragma unroll
        for (int t4 = 0; t4 < 9; ++t4) {
            int idx = (t4 * 64 + l) * 4;
            *(float4*)(gdst + idx) = *(float4*)(s_off + idx);
        }
    }
    {
        float* gdst = length + R0w * (NJ - 1);
        for (int t4 = l; t4 < 184; t4 += 64) {
            *(float4*)(gdst + t4 * 4) = *(float4*)(s_len + t4 * 4);
        }
    }
    for (int task = l; task < 32 * NJ; task += 64) {
        int r = task / NJ;
        int j = task - r * NJ;
        float jx = 0.0f, jy = 0.0f, jz = 0.0f;
        int k = j;
        while (k > 0) {
            jx += s_off[r * 72 + 3 * k + 0];
            jy += s_off[r * 72 + 3 * k + 1];
            jz += s_off[r * 72 + 3 * k + 2];
            k = c_parent[k];
        }
        long long base = (R0w + r) * (NJ * 3) + j * 3;
        joints[base + 0] = jx;
        joints[base + 1] = jy;
        joints[base + 2] = jz;
    }
#undef STAGE
#undef COMPUTE_CHUNK
}

// exact fp32 recompute of flagged rows; one block per flagged row
__global__ __launch_bounds__(256)
void fixup(const float* __restrict__ z, const float* __restrict__ W1,
           const float* __restrict__ b1, const float* __restrict__ W2,
           const float* __restrict__ b2, float* __restrict__ out,
           long long Btot, const int* __restrict__ flags)
{
    __shared__ float z_s[DD];
    __shared__ float h_s[HH];
    __shared__ float raw_s[96];
    __shared__ float off_s[72];
    int n = flags[0];
    if (n > FCAP) n = FCAP;
    if ((int)blockIdx.x >= n) return;
    const int tid = threadIdx.x;
    const long long row = flags[1 + blockIdx.x];

    float* joints  = out;
    float* offsets = out + Btot * (NJ * 3);
    float* length  = out + 2 * Btot * (NJ * 3);

    z_s[tid] = z[row * DD + tid];
    __syncthreads();
    for (int c = tid; c < HH; c += 256) {
        float acc = b1[c];
        for (int k = 0; k < DD; ++k) acc = fmaf(z_s[k], W1[k * HH + c], acc);
        h_s[c] = acc / (1.0f + expf(-acc));
    }
    __syncthreads();
    if (tid < OC) {
        float acc = b2[tid];
        for (int k = 0; k < HH; ++k) acc = fmaf(h_s[k], W2[k * OC + tid], acc);
        raw_s[tid] = acc;
    }
    __syncthreads();
    if (tid < NJ - 1) {
        int j = tid;
        float x  = raw_s[4 * j + 0];
        float y  = raw_s[4 * j + 1];
        float zz = raw_s[4 * j + 2];
        float lr = raw_s[4 * j + 3];
        float nrm = sqrtf(x * x + y * y + zz * zz);
        float inv = 1.0f / fmaxf(nrm, 1e-6f);
        float len = fmaxf(lr, 0.0f) + log1pf(expf(-fabsf(lr)));
        off_s[3 * (j + 1) + 0] = x * inv * len;
        off_s[3 * (j + 1) + 1] = y * inv * len;
        off_s[3 * (j + 1) + 2] = zz * inv * len;
        length[row * (NJ - 1) + j] = len;
    }
    if (tid < 3) off_s[tid] = 0.0f;
    __syncthreads();
    if (tid < NJ) {
        int j = tid;
        float jx = 0.0f, jy = 0.0f, jz = 0.0f;
        int k = j;
        while (k > 0) {
            jx += off_s[3 * k + 0];
            jy += off_s[3 * k + 1];
            jz += off_s[3 * k + 2];
            k = c_parent[k];
        }
        joints[row * (NJ * 3) + j * 3 + 0] = jx;
        joints[row * (NJ * 3) + j * 3 + 1] = jy;
        joints[row * (NJ * 3) + j * 3 + 2] = jz;
    }
    if (tid < NJ * 3) offsets[row * (NJ * 3) + tid] = off_s[tid];
}

extern "C" void kernel_launch(void* const* d_in, const int* in_sizes, int n_in,
                              void* d_out, int out_size, void* d_ws, size_t ws_size,
                              hipStream_t stream) {
    const float* z  = (const float*)d_in[0];
    const float* W1 = (const float*)d_in[1];
    const float* b1 = (const float*)d_in[2];
    const float* W2 = (const float*)d_in[3];
    const float* b2 = (const float*)d_in[4];
    float* out = (float*)d_out;
    _Float16* ws = (_Float16*)d_ws;
    int* flags = (int*)(ws + FLAG_OFF);

    const long long Btot = (long long)in_sizes[0] / DD;   // 131072

    prep<<<96, 256, 0, stream>>>(W1, W2, ws, flags);
    fused_main<<<(int)(Btot / BM), 256, 0, stream>>>(z, ws, b1, b2, out, Btot, flags);
    fixup<<<4096, 256, 0, stream>>>(z, W1, b1, W2, b2, out, Btot, flags);
}

// Round 9
// 145.833 us; speedup vs baseline: 1.0187x; 1.0187x over previous
//
#include <hip/hip_runtime.h>
#include <math.h>

typedef _Float16 half8 __attribute__((ext_vector_type(8)));
typedef float floatx4 __attribute__((ext_vector_type(4)));

#define DD 256
#define HH 512
#define OC 92
#define NJ 24
#define BM 128                 // rows per block (4 waves x 32)
#define NCHUNK 16
#define W2P_OFF 131072         // halfs: padded W2 frag region (16 chunks x 4096 halfs)
#define FLAG_OFF 196608        // halfs offset of int flag block
#define FCAP 16384
#define BUF_BYTES 24576        // 16KB W1 chunk + 8KB padded W2 chunk

__constant__ int c_parent[NJ] = {-1,0,0,0,1,2,3,4,5,6,7,8,9,9,9,12,13,14,16,17,18,19,20,21};

// fragment maps (verified R2-R8):
// A/B-frag: lane l holds (non-K idx)=l&15, k = 4*(l>>4)+(j&3)+16*(j>>2)
// C/D: reg i: M-idx = 4*(l>>4)+i, N-idx = l&15
// Swapped GEMM1: mfma(W1frag, zfrag) -> lane holds batch-row=l&15, h-col=16*cf+4*(l>>4)+i
//   == GEMM2 B-frag with j = i|(cf<<2)  (register handoff, no LDS bounce)
// Swapped GEMM2: lane holds batch-row=l&15, out-col=16*cf+4*(l>>4)+i -> joint lane-local.

__global__ __launch_bounds__(256)
void prep(const float* __restrict__ W1, const float* __restrict__ W2,
          _Float16* __restrict__ ws, int* __restrict__ flags) {
    int t = blockIdx.x * 256 + threadIdx.x;     // 0..24575
    if (t == 0) flags[0] = 0;
    if (t < 16384) {
        // W1 frags: lane=t&63, cfrag=(t>>6)&1, ks=(t>>7)&7, ckI=t>>10
        int lane = t & 63;
        int cfrag = (t >> 6) & 1;
        int ks = (t >> 7) & 7;
        int ckI = t >> 10;
        int c = ckI * 32 + cfrag * 16 + (lane & 15);
        int kb = ks * 32 + 4 * (lane >> 4);
        half8 v;
        #pragma unroll
        for (int j = 0; j < 8; ++j) {
            int k = kb + (j & 3) + 16 * (j >> 2);
            v[j] = (_Float16)W1[k * HH + c];
        }
        *(half8*)(ws + t * 8) = v;
    } else {
        // padded W2 frags: 16 chunks x 8 slots x 64 lanes (slots 6,7 = zero pad)
        int u = t - 16384;                      // 0..8191
        int lane = u & 63;
        int s = (u >> 6) & 7;
        int ck = u >> 9;
        half8 v;
        if (s < 6) {
            int c = s * 16 + (lane & 15);
            int kb = ck * 32 + 4 * (lane >> 4);
            #pragma unroll
            for (int j = 0; j < 8; ++j) {
                int k = kb + (j & 3) + 16 * (j >> 2);
                v[j] = (c < OC) ? (_Float16)W2[k * OC + c] : (_Float16)0.0f;
            }
        } else {
            #pragma unroll
            for (int j = 0; j < 8; ++j) v[j] = (_Float16)0.0f;
        }
        *(half8*)(ws + W2P_OFF + ck * 4096 + (s * 64 + lane) * 8) = v;
    }
}

__global__ __launch_bounds__(256)
__attribute__((amdgpu_waves_per_eu(2, 4)))
void fused_main(const float* __restrict__ z, const _Float16* __restrict__ wsp,
                const float* __restrict__ b1, const float* __restrict__ b2,
                float* __restrict__ out, long long Btot, int* __restrict__ flags)
{
    __shared__ __align__(16) char smem[2 * BUF_BYTES + 2048 + 384];  // 51584 B
    float* b1f = (float*)(smem + 2 * BUF_BYTES);          // 512 f32
    float* b2f = (float*)(smem + 2 * BUF_BYTES + 2048);   // 96 f32
    const int tid = threadIdx.x;
    const int w   = tid >> 6;
    const int l   = tid & 63;
    const int l15 = l & 15;
    const int l4  = l >> 4;

    const long long R0  = (long long)blockIdx.x * BM;
    const long long R0w = R0 + w * 32;

// async stage of one chunk's W frags (24 x 1KB granules; wave w does 6)
#define STAGE(ck_, dstbuf_) do {                                                             \
    const char* s1g_ = (const char*)wsp + (size_t)(ck_) * 16384;                             \
    const char* s2g_ = (const char*)(wsp + W2P_OFF) + (size_t)(ck_) * 8192;                  \
    _Pragma("unroll")                                                                        \
    for (int i_ = 0; i_ < 6; ++i_) {                                                         \
        int g_ = w * 6 + i_;                                                                 \
        const char* src_ = (g_ < 16) ? (s1g_ + g_ * 1024) : (s2g_ + (g_ - 16) * 1024);       \
        __builtin_amdgcn_global_load_lds(                                                    \
            (const __attribute__((address_space(1))) void*)(src_ + l * 16),                  \
            (__attribute__((address_space(3))) void*)((dstbuf_) + g_ * 1024), 16, 0, 0);     \
    }                                                                                        \
} while (0)

#define MF(a_, b_, c_) __builtin_amdgcn_mfma_f32_16x16x32_f16((a_), (b_), (c_), 0, 0, 0)
#define RD1(dst_, f_)  dst_ = *(const half8*)(s1_ + ((f_) * 64 + l) * 8)
#define FENCE()        __builtin_amdgcn_sched_barrier(0)

// Fence-pinned schedule per chunk:
//   [RD c0] | [RD c1 || MFMA c0] | [RD c2 || MFMA c1] | [RD c3 || MFMA c2]
//   | [RD vb1+w2f || MFMA c3] | [silu] [GEMM2]
// Reads pipeline on the LDS pipe with counted lgkmcnt; each MFMA cluster
// overlaps the next read cluster.  A/B register alternation bounds liveness.
#define COMPUTE_CHUNK(bufc_, ck_) do {                                                       \
    const _Float16* s1_ = (const _Float16*)(bufc_);                                          \
    const _Float16* s2_ = (const _Float16*)((bufc_) + 16384);                                \
    floatx4 acc1_[2][2];                                                                     \
    acc1_[0][0] = (floatx4)0.0f; acc1_[0][1] = (floatx4)0.0f;                                \
    acc1_[1][0] = (floatx4)0.0f; acc1_[1][1] = (floatx4)0.0f;                                \
    half8 wfA0_, wfA1_, wfA2_, wfA3_, wfB0_, wfB1_, wfB2_, wfB3_;                            \
    RD1(wfA0_, 0); RD1(wfA1_, 1); RD1(wfA2_, 2); RD1(wfA3_, 3);                              \
    FENCE();                                                                                 \
    RD1(wfB0_, 4); RD1(wfB1_, 5); RD1(wfB2_, 6); RD1(wfB3_, 7);                              \
    acc1_[0][0] = MF(wfA0_, zh[0][0], acc1_[0][0]);                                          \
    acc1_[1][0] = MF(wfA0_, zh[1][0], acc1_[1][0]);                                          \
    acc1_[0][1] = MF(wfA1_, zh[0][0], acc1_[0][1]);                                          \
    acc1_[1][1] = MF(wfA1_, zh[1][0], acc1_[1][1]);                                          \
    acc1_[0][0] = MF(wfA2_, zh[0][1], acc1_[0][0]);                                          \
    acc1_[1][0] = MF(wfA2_, zh[1][1], acc1_[1][0]);                                          \
    acc1_[0][1] = MF(wfA3_, zh[0][1], acc1_[0][1]);                                          \
    acc1_[1][1] = MF(wfA3_, zh[1][1], acc1_[1][1]);                                          \
    FENCE();                                                                                 \
    RD1(wfA0_, 8); RD1(wfA1_, 9); RD1(wfA2_, 10); RD1(wfA3_, 11);                            \
    acc1_[0][0] = MF(wfB0_, zh[0][2], acc1_[0][0]);                                          \
    acc1_[1][0] = MF(wfB0_, zh[1][2], acc1_[1][0]);                                          \
    acc1_[0][1] = MF(wfB1_, zh[0][2], acc1_[0][1]);                                          \
    acc1_[1][1] = MF(wfB1_, zh[1][2], acc1_[1][1]);                                          \
    acc1_[0][0] = MF(wfB2_, zh[0][3], acc1_[0][0]);                                          \
    acc1_[1][0] = MF(wfB2_, zh[1][3], acc1_[1][0]);                                          \
    acc1_[0][1] = MF(wfB3_, zh[0][3], acc1_[0][1]);                                          \
    acc1_[1][1] = MF(wfB3_, zh[1][3], acc1_[1][1]);                                          \
    FENCE();                                                                                 \
    RD1(wfB0_, 12); RD1(wfB1_, 13); RD1(wfB2_, 14); RD1(wfB3_, 15);                          \
    acc1_[0][0] = MF(wfA0_, zh[0][4], acc1_[0][0]);                                          \
    acc1_[1][0] = MF(wfA0_, zh[1][4], acc1_[1][0]);                                          \
    acc1_[0][1] = MF(wfA1_, zh[0][4], acc1_[0][1]);                                          \
    acc1_[1][1] = MF(wfA1_, zh[1][4], acc1_[1][1]);                                          \
    acc1_[0][0] = MF(wfA2_, zh[0][5], acc1_[0][0]);                                          \
    acc1_[1][0] = MF(wfA2_, zh[1][5], acc1_[1][0]);                                          \
    acc1_[0][1] = MF(wfA3_, zh[0][5], acc1_[0][1]);                                          \
    acc1_[1][1] = MF(wfA3_, zh[1][5], acc1_[1][1]);                                          \
    FENCE();                                                                                 \
    floatx4 vb1a_ = *(const floatx4*)(b1f + (ck_) * 32 + 4 * l4);                            \
    floatx4 vb1b_ = *(const floatx4*)(b1f + (ck_) * 32 + 16 + 4 * l4);                       \
    half8 w2f0_ = *(const half8*)(s2_ + (0 * 64 + l) * 8);                                   \
    half8 w2f1_ = *(const half8*)(s2_ + (1 * 64 + l) * 8);                                   \
    half8 w2f2_ = *(const half8*)(s2_ + (2 * 64 + l) * 8);                                   \
    half8 w2f3_ = *(const half8*)(s2_ + (3 * 64 + l) * 8);                                   \
    half8 w2f4_ = *(const half8*)(s2_ + (4 * 64 + l) * 8);                                   \
    half8 w2f5_ = *(const half8*)(s2_ + (5 * 64 + l) * 8);                                   \
    acc1_[0][0] = MF(wfB0_, zh[0][6], acc1_[0][0]);                                          \
    acc1_[1][0] = MF(wfB0_, zh[1][6], acc1_[1][0]);                                          \
    acc1_[0][1] = MF(wfB1_, zh[0][6], acc1_[0][1]);                                          \
    acc1_[1][1] = MF(wfB1_, zh[1][6], acc1_[1][1]);                                          \
    acc1_[0][0] = MF(wfB2_, zh[0][7], acc1_[0][0]);                                          \
    acc1_[1][0] = MF(wfB2_, zh[1][7], acc1_[1][0]);                                          \
    acc1_[0][1] = MF(wfB3_, zh[0][7], acc1_[0][1]);                                          \
    acc1_[1][1] = MF(wfB3_, zh[1][7], acc1_[1][1]);                                          \
    FENCE();                                                                                 \
    half8 ah_[2];                                                                            \
    _Pragma("unroll")                                                                        \
    for (int at_ = 0; at_ < 2; ++at_) {                                                      \
        _Pragma("unroll")                                                                    \
        for (int cf_ = 0; cf_ < 2; ++cf_) {                                                  \
            _Pragma("unroll")                                                                \
            for (int i_ = 0; i_ < 4; ++i_) {                                                 \
                float a_ = acc1_[at_][cf_][i_] + (cf_ ? vb1b_[i_] : vb1a_[i_]);              \
                float hv_ = a_ * __builtin_amdgcn_rcpf(1.0f + __expf(-a_));                  \
                ah_[at_][i_ | (cf_ << 2)] = (_Float16)hv_;                                   \
            }                                                                                \
        }                                                                                    \
    }                                                                                        \
    a2[0][0] = MF(w2f0_, ah_[0], a2[0][0]);                                                  \
    a2[1][0] = MF(w2f0_, ah_[1], a2[1][0]);                                                  \
    a2[0][1] = MF(w2f1_, ah_[0], a2[0][1]);                                                  \
    a2[1][1] = MF(w2f1_, ah_[1], a2[1][1]);                                                  \
    a2[0][2] = MF(w2f2_, ah_[0], a2[0][2]);                                                  \
    a2[1][2] = MF(w2f2_, ah_[1], a2[1][2]);                                                  \
    a2[0][3] = MF(w2f3_, ah_[0], a2[0][3]);                                                  \
    a2[1][3] = MF(w2f3_, ah_[1], a2[1][3]);                                                  \
    a2[0][4] = MF(w2f4_, ah_[0], a2[0][4]);                                                  \
    a2[1][4] = MF(w2f4_, ah_[1], a2[1][4]);                                                  \
    a2[0][5] = MF(w2f5_, ah_[0], a2[0][5]);                                                  \
    a2[1][5] = MF(w2f5_, ah_[1], a2[1][5]);                                                  \
} while (0)

    // ---- prologue: stage chunk 0, biases to LDS, z fragments to regs ----
    STAGE(0, smem);
    if (tid < 128) *(floatx4*)(b1f + tid * 4) = *(const floatx4*)(b1 + tid * 4);
    if (tid >= 128 && tid < 224) { int c = tid - 128; b2f[c] = (c < OC) ? b2[c] : 0.0f; }

    half8 zh[2][8];
    #pragma unroll
    for (int at = 0; at < 2; ++at) {
        const float* zrow = z + (R0w + (long long)(at * 16 + l15)) * DD;
        #pragma unroll
        for (int ks = 0; ks < 8; ++ks) {
            const float* p = zrow + ks * 32 + l4 * 4;
            floatx4 va = *(const floatx4*)p;
            floatx4 vb = *(const floatx4*)(p + 16);
            half8 th;
            th[0] = (_Float16)va[0]; th[1] = (_Float16)va[1];
            th[2] = (_Float16)va[2]; th[3] = (_Float16)va[3];
            th[4] = (_Float16)vb[0]; th[5] = (_Float16)vb[1];
            th[6] = (_Float16)vb[2]; th[7] = (_Float16)vb[3];
            zh[at][ks] = th;
        }
    }

    floatx4 a2[2][6];
    #pragma unroll
    for (int at = 0; at < 2; ++at)
        #pragma unroll
        for (int i = 0; i < 6; ++i) a2[at][i] = (floatx4)0.0f;

    __syncthreads();   // drains stage-0 DMA + bias writes

    // ---- main loop: double-buffered, one raw barrier per chunk ----
    #pragma unroll 1
    for (int t = 0; t < 8; ++t) {
        STAGE(2 * t + 1, smem + BUF_BYTES);
        COMPUTE_CHUNK(smem, 2 * t);
        asm volatile("s_waitcnt vmcnt(0)" ::: "memory");
        __builtin_amdgcn_s_barrier();
        if (t < 7) STAGE(2 * t + 2, smem);
        COMPUTE_CHUNK(smem + BUF_BYTES, 2 * t + 1);
        asm volatile("s_waitcnt vmcnt(0)" ::: "memory");
        __builtin_amdgcn_s_barrier();
    }

    // ---- epilogue (aliases staging buffers; all waves past final barrier) ----
    float* s_off = (float*)smem + w * 3040;
    float* s_len = s_off + 2304;

    #pragma unroll
    for (int at = 0; at < 2; ++at) {
        const int r = at * 16 + l15;
        #pragma unroll
        for (int cf = 0; cf < 6; ++cf) {
            const int j = 4 * cf + l4;               // joint-1 index
            if (j < NJ - 1) {
                float x  = a2[at][cf][0] + b2f[4 * j + 0];
                float y  = a2[at][cf][1] + b2f[4 * j + 1];
                float zz = a2[at][cf][2] + b2f[4 * j + 2];
                float lr = a2[at][cf][3] + b2f[4 * j + 3];
                float nrm = sqrtf(x * x + y * y + zz * zz);
                float inv = __builtin_amdgcn_rcpf(fmaxf(nrm, 1e-6f));
                float len = fmaxf(lr, 0.0f) + __logf(1.0f + __expf(-fabsf(lr)));
                if (len > 12.0f * nrm) {             // fp16 path untrustworthy here
                    int fi = atomicAdd(&flags[0], 1);
                    if (fi < FCAP) flags[1 + fi] = (int)(R0w + r);
                }
                s_off[r * 72 + 3 * (j + 1) + 0] = x * inv * len;
                s_off[r * 72 + 3 * (j + 1) + 1] = y * inv * len;
                s_off[r * 72 + 3 * (j + 1) + 2] = zz * inv * len;
                s_len[r * 23 + j] = len;
            }
        }
    }
    if (l < 32) {
        s_off[l * 72 + 0] = 0.0f;
        s_off[l * 72 + 1] = 0.0f;
        s_off[l * 72 + 2] = 0.0f;
    }
    __syncthreads();

    float* joints  = out;
    float* offsets = out + Btot * (NJ * 3);
    float* length  = out + 2 * Btot * (NJ * 3);

    {
        float* gdst = offsets + R0w * (NJ * 3);
        #pragma unroll
        for (int t4 = 0; t4 < 9; ++t4) {
            int idx = (t4 * 64 + l) * 4;
            *(float4*)(gdst + idx) = *(float4*)(s_off + idx);
        }
    }
    {
        float* gdst = length + R0w * (NJ - 1);
        for (int t4 = l; t4 < 184; t4 += 64) {
            *(float4*)(gdst + t4 * 4) = *(float4*)(s_len + t4 * 4);
        }
    }
    for (int task = l; task < 32 * NJ; task += 64) {
        int r = task / NJ;
        int j = task - r * NJ;
        float jx = 0.0f, jy = 0.0f, jz = 0.0f;
        int k = j;
        while (k > 0) {
            jx += s_off[r * 72 + 3 * k + 0];
            jy += s_off[r * 72 + 3 * k + 1];
            jz += s_off[r * 72 + 3 * k + 2];
            k = c_parent[k];
        }
        long long base = (R0w + r) * (NJ * 3) + j * 3;
        joints[base + 0] = jx;
        joints[base + 1] = jy;
        joints[base + 2] = jz;
    }
#undef STAGE
#undef COMPUTE_CHUNK
#undef MF
#undef RD1
#undef FENCE
}

// exact fp32 recompute of flagged rows; one block per flagged row
__global__ __launch_bounds__(256)
void fixup(const float* __restrict__ z, const float* __restrict__ W1,
           const float* __restrict__ b1, const float* __restrict__ W2,
           const float* __restrict__ b2, float* __restrict__ out,
           long long Btot, const int* __restrict__ flags)
{
    __shared__ float z_s[DD];
    __shared__ float h_s[HH];
    __shared__ float raw_s[96];
    __shared__ float off_s[72];
    int n = flags[0];
    if (n > FCAP) n = FCAP;
    if ((int)blockIdx.x >= n) return;
    const int tid = threadIdx.x;
    const long long row = flags[1 + blockIdx.x];

    float* joints  = out;
    float* offsets = out + Btot * (NJ * 3);
    float* length  = out + 2 * Btot * (NJ * 3);

    z_s[tid] = z[row * DD + tid];
    __syncthreads();
    for (int c = tid; c < HH; c += 256) {
        float acc = b1[c];
        for (int k = 0; k < DD; ++k) acc = fmaf(z_s[k], W1[k * HH + c], acc);
        h_s[c] = acc / (1.0f + expf(-acc));
    }
    __syncthreads();
    if (tid < OC) {
        float acc = b2[tid];
        for (int k = 0; k < HH; ++k) acc = fmaf(h_s[k], W2[k * OC + tid], acc);
        raw_s[tid] = acc;
    }
    __syncthreads();
    if (tid < NJ - 1) {
        int j = tid;
        float x  = raw_s[4 * j + 0];
        float y  = raw_s[4 * j + 1];
        float zz = raw_s[4 * j + 2];
        float lr = raw_s[4 * j + 3];
        float nrm = sqrtf(x * x + y * y + zz * zz);
        float inv = 1.0f / fmaxf(nrm, 1e-6f);
        float len = fmaxf(lr, 0.0f) + log1pf(expf(-fabsf(lr)));
        off_s[3 * (j + 1) + 0] = x * inv * len;
        off_s[3 * (j + 1) + 1] = y * inv * len;
        off_s[3 * (j + 1) + 2] = zz * inv * len;
        length[row * (NJ - 1) + j] = len;
    }
    if (tid < 3) off_s[tid] = 0.0f;
    __syncthreads();
    if (tid < NJ) {
        int j = tid;
        float jx = 0.0f, jy = 0.0f, jz = 0.0f;
        int k = j;
        while (k > 0) {
            jx += off_s[3 * k + 0];
            jy += off_s[3 * k + 1];
            jz += off_s[3 * k + 2];
            k = c_parent[k];
        }
        joints[row * (NJ * 3) + j * 3 + 0] = jx;
        joints[row * (NJ * 3) + j * 3 + 1] = jy;
        joints[row * (NJ * 3) + j * 3 + 2] = jz;
    }
    if (tid < NJ * 3) offsets[row * (NJ * 3) + tid] = off_s[tid];
}

extern "C" void kernel_launch(void* const* d_in, const int* in_sizes, int n_in,
                              void* d_out, int out_size, void* d_ws, size_t ws_size,
                              hipStream_t stream) {
    const float* z  = (const float*)d_in[0];
    const float* W1 = (const float*)d_in[1];
    const float* b1 = (const float*)d_in[2];
    const float* W2 = (const float*)d_in[3];
    const float* b2 = (const float*)d_in[4];
    float* out = (float*)d_out;
    _Float16* ws = (_Float16*)d_ws;
    int* flags = (int*)(ws + FLAG_OFF);

    const long long Btot = (long long)in_sizes[0] / DD;   // 131072

    prep<<<96, 256, 0, stream>>>(W1, W2, ws, flags);
    fused_main<<<(int)(Btot / BM), 256, 0, stream>>>(z, ws, b1, b2, out, Btot, flags);
    fixup<<<4096, 256, 0, stream>>>(z, W1, b1, W2, b2, out, Btot, flags);
}